// Round 1
// baseline (2108.100 us; speedup 1.0000x reference)
//
#include <hip/hip_runtime.h>
#include <hip/hip_bf16.h>

#define N_NODES 100000
#define N_EDGES 3200000
#define ALPHA   0.1f

// ---------------------------------------------------------------------------
// Fused MLP: h = relu(x @ W1^T + b1) @ W2^T + b2     [N,512] -> [N,16]
// BM=64 rows/block, BN=256 (all hidden cols), BK=32, 512 threads.
// Register tile 8x4 per thread. GEMM2 done in-block from LDS (two 32-row
// phases) to avoid materializing h1 (100000x256) in global memory.
// LDS: phase1 As[32][68] + Bs[32][256] = 10368 f; phase2 Hs[32][260] +
// W2s[16][260] = 12480 f. Union buffer = 12480 floats = 49.9 KB -> 3 blk/CU.
// ---------------------------------------------------------------------------
__global__ __launch_bounds__(512) void mlp_kernel(
    const float* __restrict__ x, const float* __restrict__ W1,
    const float* __restrict__ b1, const float* __restrict__ W2,
    const float* __restrict__ b2, float* __restrict__ h, int n)
{
    __shared__ float buf[12480];
    float* As  = buf;           // [32][68]  transposed x tile
    float* Bs  = buf + 2176;    // [32][256] transposed W1 tile (Bs[k][c]=W1[c][k])
    float* Hs  = buf;           // [32][260] relu(h1) tile (phase)
    float* W2s = buf + 8320;    // [16][260]

    const int tid = threadIdx.x;
    const int tc  = tid & 63;   // col group: cols tc*4 .. tc*4+3
    const int tr  = tid >> 6;   // row group: rows tr*8 .. tr*8+7 (uniform per wave)
    const int row0 = blockIdx.x * 64;

    float acc[8][4];
#pragma unroll
    for (int i = 0; i < 8; ++i)
#pragma unroll
        for (int j = 0; j < 4; ++j) acc[i][j] = 0.f;

    // staging assignments
    const int a_r = tid >> 3;          // 0..63
    const int a_k = (tid & 7) * 4;     // 0..28
    const int b_n = tid >> 1;          // 0..255
    const int b_k = (tid & 1) * 16;    // 0 or 16

    for (int kk = 0; kk < 512; kk += 32) {
        // global loads
        float4 av = make_float4(0.f, 0.f, 0.f, 0.f);
        const int grow = row0 + a_r;
        if (grow < n) av = *(const float4*)(x + (size_t)grow * 512 + kk + a_k);
        float4 bv[4];
#pragma unroll
        for (int q = 0; q < 4; ++q)
            bv[q] = *(const float4*)(W1 + (size_t)b_n * 512 + kk + b_k + q * 4);

        __syncthreads();   // previous iteration's LDS reads complete
        As[(a_k + 0) * 68 + a_r] = av.x;
        As[(a_k + 1) * 68 + a_r] = av.y;
        As[(a_k + 2) * 68 + a_r] = av.z;
        As[(a_k + 3) * 68 + a_r] = av.w;
#pragma unroll
        for (int q = 0; q < 4; ++q) {
            Bs[(b_k + q * 4 + 0) * 256 + b_n] = bv[q].x;
            Bs[(b_k + q * 4 + 1) * 256 + b_n] = bv[q].y;
            Bs[(b_k + q * 4 + 2) * 256 + b_n] = bv[q].z;
            Bs[(b_k + q * 4 + 3) * 256 + b_n] = bv[q].w;
        }
        __syncthreads();

#pragma unroll
        for (int k = 0; k < 32; ++k) {
            float4 a01 = *(float4*)(As + k * 68 + tr * 8);
            float4 a23 = *(float4*)(As + k * 68 + tr * 8 + 4);
            float4 bq  = *(float4*)(Bs + k * 256 + tc * 4);
            float ar[8] = {a01.x, a01.y, a01.z, a01.w, a23.x, a23.y, a23.z, a23.w};
            float br[4] = {bq.x, bq.y, bq.z, bq.w};
#pragma unroll
            for (int i = 0; i < 8; ++i)
#pragma unroll
                for (int j = 0; j < 4; ++j) acc[i][j] = fmaf(ar[i], br[j], acc[i][j]);
        }
    }

    // bias + relu
    const float4 b1v = *(const float4*)(b1 + tc * 4);
    const float bb[4] = {b1v.x, b1v.y, b1v.z, b1v.w};
#pragma unroll
    for (int i = 0; i < 8; ++i)
#pragma unroll
        for (int j = 0; j < 4; ++j) acc[i][j] = fmaxf(acc[i][j] + bb[j], 0.f);

    // GEMM2: two phases of 32 rows
    const int n_l = tid >> 4;   // 0..31
    const int cc  = tid & 15;
    const float b2v = b2[cc];
#pragma unroll
    for (int p = 0; p < 2; ++p) {
        __syncthreads();   // K-loop / previous phase LDS reads complete
        if ((tr >> 2) == p) {
            const int trr = tr & 3;
#pragma unroll
            for (int i = 0; i < 8; ++i) {
                const int r = trr * 8 + i;
                *(float4*)(Hs + r * 260 + tc * 4) =
                    make_float4(acc[i][0], acc[i][1], acc[i][2], acc[i][3]);
            }
        }
        if (p == 0) {
            const int rw = tid >> 5, kw = (tid & 31) * 8;
            float4 w0 = *(const float4*)(W2 + rw * 256 + kw);
            float4 w1 = *(const float4*)(W2 + rw * 256 + kw + 4);
            *(float4*)(W2s + rw * 260 + kw)     = w0;
            *(float4*)(W2s + rw * 260 + kw + 4) = w1;
        }
        __syncthreads();
        float s = 0.f;
#pragma unroll 8
        for (int k4 = 0; k4 < 64; ++k4) {
            float4 hv = *(float4*)(Hs + n_l * 260 + k4 * 4);
            float4 wv = *(float4*)(W2s + cc * 260 + k4 * 4);
            s += hv.x * wv.x + hv.y * wv.y + hv.z * wv.z + hv.w * wv.w;
        }
        const int node = row0 + p * 32 + n_l;
        if (node < n) h[(size_t)node * 16 + cc] = s + b2v;
    }
}

// ---------------------------------------------------------------------------
// CSR build: histogram of dst, dinv, 1-block scan, scatter into dst-sorted
// edge list with precomputed norm = dinv[src]*dinv[dst].
// ---------------------------------------------------------------------------
__global__ void hist_kernel(const int* __restrict__ dst, int* __restrict__ cnt, int e)
{
    int i = blockIdx.x * blockDim.x + threadIdx.x;
    if (i < e) atomicAdd(&cnt[dst[i]], 1);
}

__global__ void dinv_kernel(const int* __restrict__ cnt, float* __restrict__ dinv, int n)
{
    int i = blockIdx.x * blockDim.x + threadIdx.x;
    if (i < n) dinv[i] = rsqrtf((float)cnt[i] + 1.0f);  // +1 self loop; deg>=1 always
}

__global__ __launch_bounds__(1024) void scan_kernel(
    const int* __restrict__ cnt, int* __restrict__ row_start,
    int* __restrict__ cursor, int n, int total)
{
    __shared__ int sm[1024];
    const int i = threadIdx.x;
    const int CH = (n + 1023) / 1024;
    const int base = i * CH;
    int s = 0;
    for (int j = 0; j < CH; ++j) {
        int idx = base + j;
        if (idx < n) s += cnt[idx];
    }
    sm[i] = s;
    __syncthreads();
    for (int off = 1; off < 1024; off <<= 1) {
        int v = 0;
        if (i >= off) v = sm[i - off];
        __syncthreads();
        sm[i] += v;
        __syncthreads();
    }
    int run = sm[i] - s;  // exclusive prefix
    for (int j = 0; j < CH; ++j) {
        int idx = base + j;
        if (idx < n) {
            row_start[idx] = run;
            cursor[idx]    = run;
            run += cnt[idx];
        }
    }
    if (i == 0) row_start[n] = total;
}

__global__ void scatter_kernel(
    const int* __restrict__ src, const int* __restrict__ dst,
    const float* __restrict__ dinv, int* __restrict__ cursor,
    int* __restrict__ csr_src, float* __restrict__ csr_norm, int e)
{
    int i = blockIdx.x * blockDim.x + threadIdx.x;
    if (i < e) {
        int s = src[i], d = dst[i];
        int pos = atomicAdd(&cursor[d], 1);
        csr_src[pos]  = s;
        csr_norm[pos] = dinv[s] * dinv[d];
    }
}

// ---------------------------------------------------------------------------
// One propagation step (gather form, no atomics). 16 lanes = one node (one
// lane per class); z-row gathers are single 64B coalesced lines. Self-loop
// handled inline. Last step fuses log_softmax via 16-lane shuffles.
// ---------------------------------------------------------------------------
__global__ __launch_bounds__(256) void prop_kernel(
    const int* __restrict__ row_start, const int* __restrict__ csr_src,
    const float* __restrict__ csr_norm, const float* __restrict__ dinv,
    const float* __restrict__ zin, const float* __restrict__ h,
    float* __restrict__ zout, int n, int is_last)
{
    const int g = blockIdx.x * 16 + (threadIdx.x >> 4);
    const int f = threadIdx.x & 15;
    if (g >= n) return;
    const float di = dinv[g];
    float acc = di * di * zin[(size_t)g * 16 + f];
    const int s = row_start[g], e = row_start[g + 1];
    for (int j = s; j < e; ++j) {
        int   cs = csr_src[j];
        float cn = csr_norm[j];
        acc = fmaf(cn, zin[(size_t)cs * 16 + f], acc);
    }
    const float znew = fmaf(1.0f - ALPHA, acc, ALPHA * h[(size_t)g * 16 + f]);
    if (!is_last) {
        zout[(size_t)g * 16 + f] = znew;
    } else {
        float m = znew;
#pragma unroll
        for (int w = 1; w < 16; w <<= 1) m = fmaxf(m, __shfl_xor(m, w, 16));
        float ex = expf(znew - m);
        float ss = ex;
#pragma unroll
        for (int w = 1; w < 16; w <<= 1) ss += __shfl_xor(ss, w, 16);
        zout[(size_t)g * 16 + f] = (znew - m) - logf(ss);
    }
}

// ---------------------------------------------------------------------------
extern "C" void kernel_launch(void* const* d_in, const int* in_sizes, int n_in,
                              void* d_out, int out_size, void* d_ws, size_t ws_size,
                              hipStream_t stream)
{
    const float* x  = (const float*)d_in[0];
    const float* W1 = (const float*)d_in[1];
    const float* b1 = (const float*)d_in[2];
    const float* W2 = (const float*)d_in[3];
    const float* b2 = (const float*)d_in[4];
    const int*   ei = (const int*)d_in[5];

    const int N = N_NODES;
    const int E = N_EDGES;
    const int* srcp = ei;       // edge_index[0]
    const int* dstp = ei + E;   // edge_index[1]

    float* ws = (float*)d_ws;
    float* h        = ws;                       // 1,600,000 f
    float* ZA       = ws + 1600000;             // 1,600,000 f
    float* ZB       = ws + 3200000;             // 1,600,000 f
    float* dinv     = ws + 4800000;             // 100,000 f
    int*   cnt      = (int*)(ws + 4900000);     // 100,000 i
    int*   row_st   = (int*)(ws + 5000000);     // 100,001 i (padded to 100004)
    int*   cursor   = (int*)(ws + 5100004);     // 100,000 i
    int*   csr_src  = (int*)(ws + 5200004);     // 3,200,000 i
    float* csr_norm = ws + 8400004;             // 3,200,000 f
    // total ~46.4 MB

    hipMemsetAsync(cnt, 0, (size_t)N * sizeof(int), stream);
    hist_kernel<<<(E + 255) / 256, 256, 0, stream>>>(dstp, cnt, E);
    dinv_kernel<<<(N + 255) / 256, 256, 0, stream>>>(cnt, dinv, N);
    scan_kernel<<<1, 1024, 0, stream>>>(cnt, row_st, cursor, N, E);
    scatter_kernel<<<(E + 255) / 256, 256, 0, stream>>>(srcp, dstp, dinv, cursor,
                                                        csr_src, csr_norm, E);
    mlp_kernel<<<(N + 63) / 64, 512, 0, stream>>>(x, W1, b1, W2, b2, h, N);

    const float* zin = h;
    for (int k = 0; k < 10; ++k) {
        const bool last = (k == 9);
        float* zo = last ? (float*)d_out : ((k & 1) ? ZB : ZA);
        prop_kernel<<<(N + 15) / 16, 256, 0, stream>>>(row_st, csr_src, csr_norm,
                                                       dinv, zin, h, zo, N,
                                                       last ? 1 : 0);
        zin = zo;
    }
}

// Round 2
// 1708.049 us; speedup vs baseline: 1.2342x; 1.2342x over previous
//
#include <hip/hip_runtime.h>
#include <hip/hip_bf16.h>
#include <stdint.h>

#define N_NODES 100000
#define N_EDGES 3200000
#define ALPHA   0.1f

typedef __attribute__((ext_vector_type(8))) short v8s;   // 8 x bf16 (4 VGPR)
typedef __attribute__((ext_vector_type(4))) float f32x4; // MFMA acc

// --- bf16 hi/lo split helpers (RNE) ------------------------------------
__device__ __forceinline__ uint32_t bf16_rne(float f) {
    uint32_t u = __float_as_uint(f);
    return (u + 0x7FFFu + ((u >> 16) & 1u)) >> 16;
}
__device__ __forceinline__ float bf16_f32(uint32_t b) { return __uint_as_float(b << 16); }

// ---------------------------------------------------------------------------
// Pre-convert W1 [256][512] fp32 into hi/lo bf16 chunks laid out exactly as
// the GEMM1 LDS image: W1p[ks][h][chunk], chunk = quad*2 + (0=hi8,1=lo8),
// each chunk = 16B (8 bf16 covering k = ks*32 + quad*8 .. +7).
// ---------------------------------------------------------------------------
__global__ __launch_bounds__(256) void w1_convert_kernel(
    const float* __restrict__ W1, uint4* __restrict__ W1p)
{
    int tid = blockIdx.x * 256 + threadIdx.x;   // 16384 total
    int hh  = tid >> 6;                          // 0..255 hidden
    int g   = tid & 63;                          // 8-k group
    int ks  = g >> 2, q = g & 3;
    const float* src = W1 + (size_t)hh * 512 + g * 8;
    float4 f0 = *(const float4*)(src);
    float4 f1 = *(const float4*)(src + 4);
    float f[8] = {f0.x, f0.y, f0.z, f0.w, f1.x, f1.y, f1.z, f1.w};
    uint32_t hi[8], lo[8];
#pragma unroll
    for (int j = 0; j < 8; ++j) {
        hi[j] = bf16_rne(f[j]);
        lo[j] = bf16_rne(f[j] - bf16_f32(hi[j]));
    }
    uint4 H = make_uint4(hi[0] | (hi[1] << 16), hi[2] | (hi[3] << 16),
                         hi[4] | (hi[5] << 16), hi[6] | (hi[7] << 16));
    uint4 L = make_uint4(lo[0] | (lo[1] << 16), lo[2] | (lo[3] << 16),
                         lo[4] | (lo[5] << 16), lo[6] | (lo[7] << 16));
    size_t base = (size_t)(ks * 256 + hh) * 8;   // chunk index
    W1p[base + q * 2]     = H;
    W1p[base + q * 2 + 1] = L;
}

// ---------------------------------------------------------------------------
// Fused MLP via MFMA 16x16x32 bf16 with hi/lo split (fp32-accurate).
// Computes h1^T = W1 * x^T per block (A=W1 m=hidden, B=x n=node) so each
// lane's C regs hold 4 consecutive HIDDEN values for one node -> GEMM2
// (h2 = relu(h1) @ W2^T) runs in registers in fp32, reduced over waves in LDS.
// Block: 64 nodes, 256 hidden (full), 256 thr (4 waves); wave w owns hidden
// 64w..64w+63 (its own GEMM2 k-range -> no cross-wave frag sharing).
// LDS rows padded to 144B (9x16) -> bank-floor reads/writes.
// ---------------------------------------------------------------------------
#define LROW 144

__global__ __launch_bounds__(256) void mlp_kernel(
    const float* __restrict__ x, const uint4* __restrict__ W1p,
    const float* __restrict__ b1, const float* __restrict__ W2,
    const float* __restrict__ b2, float* __restrict__ h, int n)
{
    __shared__ __align__(16) char smem[46080];
    char*  W1s  = smem;                       // 256 * 144 = 36864
    char*  xs   = smem + 36864;               // 64 * 144 = 9216
    float* W2s  = (float*)smem;               // [16][260] fp32 (post K-loop)
    float* part = (float*)(smem + 16640);     // [4][64][16] fp32

    const int tid = threadIdx.x;
    const int w = tid >> 6, l = tid & 63, l15 = l & 15, q = l >> 4;
    const int row0 = blockIdx.x * 64;

    f32x4 acc[4][4];
#pragma unroll
    for (int mt = 0; mt < 4; ++mt)
#pragma unroll
        for (int nt = 0; nt < 4; ++nt) acc[mt][nt] = (f32x4){0.f, 0.f, 0.f, 0.f};

    for (int ks = 0; ks < 16; ++ks) {
        __syncthreads();
        // ---- stage W1 k-slab (32KB, pre-converted, straight copy) ----
        const uint4* wsrc = W1p + (size_t)ks * 2048 + tid;
#pragma unroll
        for (int i = 0; i < 8; ++i) {
            uint4 v = wsrc[i * 256];
            int ci = tid + i * 256;           // = h*8 + chunk
            *(uint4*)(W1s + (ci >> 3) * LROW + (ci & 7) * 16) = v;
        }
        // ---- stage x k-slab with on-the-fly hi/lo split ----
#pragma unroll
        for (int i = 0; i < 2; ++i) {
            int ci = tid + i * 256;           // 0..511 ; node = ci>>3, g4 = ci&7 (4 k)
            int node = ci >> 3, g4 = ci & 7;
            int grow = row0 + node;
            float4 f = make_float4(0.f, 0.f, 0.f, 0.f);
            if (grow < n) f = *(const float4*)(x + (size_t)grow * 512 + ks * 32 + g4 * 4);
            uint32_t h0 = bf16_rne(f.x), h1 = bf16_rne(f.y),
                     h2 = bf16_rne(f.z), h3 = bf16_rne(f.w);
            uint32_t l0 = bf16_rne(f.x - bf16_f32(h0)), l1 = bf16_rne(f.y - bf16_f32(h1)),
                     l2 = bf16_rne(f.z - bf16_f32(h2)), l3 = bf16_rne(f.w - bf16_f32(h3));
            char* bp = xs + node * LROW + (g4 >> 1) * 32 + (g4 & 1) * 8;
            *(uint2*)(bp)      = make_uint2(h0 | (h1 << 16), h2 | (h3 << 16));
            *(uint2*)(bp + 16) = make_uint2(l0 | (l1 << 16), l2 | (l3 << 16));
        }
        __syncthreads();

        // ---- fragments ----
        v8s aH[4], aL[4], bH[4], bL[4];
#pragma unroll
        for (int mt = 0; mt < 4; ++mt) {
            const char* p = W1s + (w * 64 + mt * 16 + l15) * LROW + q * 32;
            aH[mt] = *(const v8s*)(p);
            aL[mt] = *(const v8s*)(p + 16);
        }
#pragma unroll
        for (int nt = 0; nt < 4; ++nt) {
            const char* p = xs + (nt * 16 + l15) * LROW + q * 32;
            bH[nt] = *(const v8s*)(p);
            bL[nt] = *(const v8s*)(p + 16);
        }
        // ---- 48 MFMA: 3-term split per (mt,nt) ----
#pragma unroll
        for (int mt = 0; mt < 4; ++mt)
#pragma unroll
            for (int nt = 0; nt < 4; ++nt) {
                f32x4 c = acc[mt][nt];
                c = __builtin_amdgcn_mfma_f32_16x16x32_bf16(aH[mt], bH[nt], c, 0, 0, 0);
                c = __builtin_amdgcn_mfma_f32_16x16x32_bf16(aH[mt], bL[nt], c, 0, 0, 0);
                c = __builtin_amdgcn_mfma_f32_16x16x32_bf16(aL[mt], bH[nt], c, 0, 0, 0);
                acc[mt][nt] = c;
            }
    }

    // ---- bias + relu (hidden = 64w + mt*16 + q*4 + r) ----
#pragma unroll
    for (int mt = 0; mt < 4; ++mt) {
        float4 bv = *(const float4*)(b1 + w * 64 + mt * 16 + q * 4);
#pragma unroll
        for (int nt = 0; nt < 4; ++nt) {
            acc[mt][nt][0] = fmaxf(acc[mt][nt][0] + bv.x, 0.f);
            acc[mt][nt][1] = fmaxf(acc[mt][nt][1] + bv.y, 0.f);
            acc[mt][nt][2] = fmaxf(acc[mt][nt][2] + bv.z, 0.f);
            acc[mt][nt][3] = fmaxf(acc[mt][nt][3] + bv.w, 0.f);
        }
    }

    __syncthreads();            // K-loop LDS reads done; overlay W2s/part
    {   // stage W2 fp32 [16][260]
        int c = tid >> 4, k16 = (tid & 15) * 16;
#pragma unroll
        for (int i = 0; i < 4; ++i)
            *(float4*)(W2s + c * 260 + k16 + i * 4) =
                *(const float4*)(W2 + c * 256 + k16 + i * 4);
    }
    __syncthreads();

    // ---- GEMM2 in registers (fp32): p[nt][c] over this wave's 64 hidden ----
    float p[4][16];
#pragma unroll
    for (int nt = 0; nt < 4; ++nt)
#pragma unroll
        for (int c = 0; c < 16; ++c) p[nt][c] = 0.f;
#pragma unroll
    for (int c = 0; c < 16; ++c)
#pragma unroll
        for (int mt = 0; mt < 4; ++mt) {
            float4 wv = *(const float4*)(W2s + c * 260 + w * 64 + mt * 16 + q * 4);
#pragma unroll
            for (int nt = 0; nt < 4; ++nt)
                p[nt][c] += acc[mt][nt][0] * wv.x + acc[mt][nt][1] * wv.y +
                            acc[mt][nt][2] * wv.z + acc[mt][nt][3] * wv.w;
        }
    // butterfly-reduce over the 4 quads (lanes ^16, ^32)
#pragma unroll
    for (int nt = 0; nt < 4; ++nt)
#pragma unroll
        for (int c = 0; c < 16; ++c) {
            p[nt][c] += __shfl_xor(p[nt][c], 16);
            p[nt][c] += __shfl_xor(p[nt][c], 32);
        }
    // each lane writes its q-quarter of classes for its 4 nodes
#pragma unroll
    for (int nt = 0; nt < 4; ++nt) {
        float4 o;
        o.x = (q < 2) ? ((q == 0) ? p[nt][0] : p[nt][4]) : ((q == 2) ? p[nt][8]  : p[nt][12]);
        o.y = (q < 2) ? ((q == 0) ? p[nt][1] : p[nt][5]) : ((q == 2) ? p[nt][9]  : p[nt][13]);
        o.z = (q < 2) ? ((q == 0) ? p[nt][2] : p[nt][6]) : ((q == 2) ? p[nt][10] : p[nt][14]);
        o.w = (q < 2) ? ((q == 0) ? p[nt][3] : p[nt][7]) : ((q == 2) ? p[nt][11] : p[nt][15]);
        int node = nt * 16 + l15;
        *(float4*)(part + ((w * 64 + node) << 4) + q * 4) = o;
    }
    __syncthreads();
    {   // final reduce across 4 waves + b2, write h
        int node = tid >> 2, i4 = (tid & 3) * 4;
        float4 s = make_float4(0.f, 0.f, 0.f, 0.f);
#pragma unroll
        for (int ww = 0; ww < 4; ++ww) {
            float4 v = *(float4*)(part + ((ww * 64 + node) << 4) + i4);
            s.x += v.x; s.y += v.y; s.z += v.z; s.w += v.w;
        }
        float4 bv = *(const float4*)(b2 + i4);
        int grow = row0 + node;
        if (grow < n) {
            *(float4*)(h + (size_t)grow * 16 + i4) =
                make_float4(s.x + bv.x, s.y + bv.y, s.z + bv.z, s.w + bv.w);
        }
    }
}

// ---------------------------------------------------------------------------
// CSR build (unchanged from R1): histogram, dinv, 1-block scan, scatter.
// ---------------------------------------------------------------------------
__global__ void hist_kernel(const int* __restrict__ dst, int* __restrict__ cnt, int e)
{
    int i = blockIdx.x * blockDim.x + threadIdx.x;
    if (i < e) atomicAdd(&cnt[dst[i]], 1);
}

__global__ void dinv_kernel(const int* __restrict__ cnt, float* __restrict__ dinv, int n)
{
    int i = blockIdx.x * blockDim.x + threadIdx.x;
    if (i < n) dinv[i] = rsqrtf((float)cnt[i] + 1.0f);
}

__global__ __launch_bounds__(1024) void scan_kernel(
    const int* __restrict__ cnt, int* __restrict__ row_start,
    int* __restrict__ cursor, int n, int total)
{
    __shared__ int sm[1024];
    const int i = threadIdx.x;
    const int CH = (n + 1023) / 1024;
    const int base = i * CH;
    int s = 0;
    for (int j = 0; j < CH; ++j) {
        int idx = base + j;
        if (idx < n) s += cnt[idx];
    }
    sm[i] = s;
    __syncthreads();
    for (int off = 1; off < 1024; off <<= 1) {
        int v = 0;
        if (i >= off) v = sm[i - off];
        __syncthreads();
        sm[i] += v;
        __syncthreads();
    }
    int run = sm[i] - s;
    for (int j = 0; j < CH; ++j) {
        int idx = base + j;
        if (idx < n) {
            row_start[idx] = run;
            cursor[idx]    = run;
            run += cnt[idx];
        }
    }
    if (i == 0) row_start[n] = total;
}

__global__ void scatter_kernel(
    const int* __restrict__ src, const int* __restrict__ dst,
    const float* __restrict__ dinv, int* __restrict__ cursor,
    int* __restrict__ csr_src, float* __restrict__ csr_norm, int e)
{
    int i = blockIdx.x * blockDim.x + threadIdx.x;
    if (i < e) {
        int s = src[i], d = dst[i];
        int pos = atomicAdd(&cursor[d], 1);
        csr_src[pos]  = s;
        csr_norm[pos] = dinv[s] * dinv[d];
    }
}

// ---------------------------------------------------------------------------
// Propagation step: 4 lanes per node, float4 per lane (whole 64B z-row per
// group), edge loop unrolled x4 -> 4 row-gathers in flight per group.
// Last step fuses log_softmax (intra-lane over 4 + shfl over the 4 lanes).
// ---------------------------------------------------------------------------
__global__ __launch_bounds__(256) void prop_kernel(
    const int* __restrict__ row_start, const int* __restrict__ csr_src,
    const float* __restrict__ csr_norm, const float* __restrict__ dinv,
    const float* __restrict__ zin, const float* __restrict__ h,
    float* __restrict__ zout, int n, int is_last)
{
    const int g  = blockIdx.x * 64 + (threadIdx.x >> 2);
    const int f4 = (threadIdx.x & 3) * 4;
    if (g >= n) return;
    const float di = dinv[g];
    const float dd = di * di;
    const float4 zi = *(const float4*)(zin + (size_t)g * 16 + f4);
    float ax = dd * zi.x, ay = dd * zi.y, az = dd * zi.z, aw = dd * zi.w;
    const int s = row_start[g], e = row_start[g + 1];
    int j = s;
    for (; j + 4 <= e; j += 4) {
        int   c0 = csr_src[j],     c1 = csr_src[j + 1];
        int   c2 = csr_src[j + 2], c3 = csr_src[j + 3];
        float n0 = csr_norm[j],     n1 = csr_norm[j + 1];
        float n2 = csr_norm[j + 2], n3 = csr_norm[j + 3];
        float4 z0 = *(const float4*)(zin + (size_t)c0 * 16 + f4);
        float4 z1 = *(const float4*)(zin + (size_t)c1 * 16 + f4);
        float4 z2 = *(const float4*)(zin + (size_t)c2 * 16 + f4);
        float4 z3 = *(const float4*)(zin + (size_t)c3 * 16 + f4);
        ax = fmaf(n0, z0.x, ax); ay = fmaf(n0, z0.y, ay); az = fmaf(n0, z0.z, az); aw = fmaf(n0, z0.w, aw);
        ax = fmaf(n1, z1.x, ax); ay = fmaf(n1, z1.y, ay); az = fmaf(n1, z1.z, az); aw = fmaf(n1, z1.w, aw);
        ax = fmaf(n2, z2.x, ax); ay = fmaf(n2, z2.y, ay); az = fmaf(n2, z2.z, az); aw = fmaf(n2, z2.w, aw);
        ax = fmaf(n3, z3.x, ax); ay = fmaf(n3, z3.y, ay); az = fmaf(n3, z3.z, az); aw = fmaf(n3, z3.w, aw);
    }
    for (; j < e; ++j) {
        int   c = csr_src[j];
        float nn = csr_norm[j];
        float4 z = *(const float4*)(zin + (size_t)c * 16 + f4);
        ax = fmaf(nn, z.x, ax); ay = fmaf(nn, z.y, ay);
        az = fmaf(nn, z.z, az); aw = fmaf(nn, z.w, aw);
    }
    const float4 hv = *(const float4*)(h + (size_t)g * 16 + f4);
    float4 zn = make_float4(fmaf(1.0f - ALPHA, ax, ALPHA * hv.x),
                            fmaf(1.0f - ALPHA, ay, ALPHA * hv.y),
                            fmaf(1.0f - ALPHA, az, ALPHA * hv.z),
                            fmaf(1.0f - ALPHA, aw, ALPHA * hv.w));
    if (!is_last) {
        *(float4*)(zout + (size_t)g * 16 + f4) = zn;
    } else {
        float m = fmaxf(fmaxf(zn.x, zn.y), fmaxf(zn.z, zn.w));
        m = fmaxf(m, __shfl_xor(m, 1));
        m = fmaxf(m, __shfl_xor(m, 2));
        float ss = expf(zn.x - m) + expf(zn.y - m) + expf(zn.z - m) + expf(zn.w - m);
        ss += __shfl_xor(ss, 1);
        ss += __shfl_xor(ss, 2);
        float ls = logf(ss);
        *(float4*)(zout + (size_t)g * 16 + f4) =
            make_float4(zn.x - m - ls, zn.y - m - ls, zn.z - m - ls, zn.w - m - ls);
    }
}

// ---------------------------------------------------------------------------
extern "C" void kernel_launch(void* const* d_in, const int* in_sizes, int n_in,
                              void* d_out, int out_size, void* d_ws, size_t ws_size,
                              hipStream_t stream)
{
    const float* x  = (const float*)d_in[0];
    const float* W1 = (const float*)d_in[1];
    const float* b1 = (const float*)d_in[2];
    const float* W2 = (const float*)d_in[3];
    const float* b2 = (const float*)d_in[4];
    const int*   ei = (const int*)d_in[5];

    const int N = N_NODES;
    const int E = N_EDGES;
    const int* srcp = ei;
    const int* dstp = ei + E;

    float* ws = (float*)d_ws;
    float* h        = ws;                       // 1,600,000 f
    float* ZA       = ws + 1600000;             // 1,600,000 f
    float* ZB       = ws + 3200000;             // 1,600,000 f
    float* dinv     = ws + 4800000;             // 100,000 f
    int*   cnt      = (int*)(ws + 4900000);     // 100,000 i
    int*   row_st   = (int*)(ws + 5000000);     // 100,001 i (pad to 100004)
    int*   cursor   = (int*)(ws + 5100004);     // 100,000 i
    int*   csr_src  = (int*)(ws + 5200004);     // 3,200,000 i
    float* csr_norm = ws + 8400004;             // 3,200,000 f
    uint4* W1p      = (uint4*)(ws + 11600004);  // 32768 x 16B = 512 KB
    // total ~46.9 MB

    hipMemsetAsync(cnt, 0, (size_t)N * sizeof(int), stream);
    hist_kernel<<<(E + 255) / 256, 256, 0, stream>>>(dstp, cnt, E);
    dinv_kernel<<<(N + 255) / 256, 256, 0, stream>>>(cnt, dinv, N);
    scan_kernel<<<1, 1024, 0, stream>>>(cnt, row_st, cursor, N, E);
    scatter_kernel<<<(E + 255) / 256, 256, 0, stream>>>(srcp, dstp, dinv, cursor,
                                                        csr_src, csr_norm, E);
    w1_convert_kernel<<<64, 256, 0, stream>>>(W1, W1p);
    mlp_kernel<<<(N + 63) / 64, 256, 0, stream>>>(x, W1p, b1, W2, b2, h, N);

    const float* zin = h;
    for (int k = 0; k < 10; ++k) {
        const bool last = (k == 9);
        float* zo = last ? (float*)d_out : ((k & 1) ? ZB : ZA);
        prop_kernel<<<(N + 63) / 64, 256, 0, stream>>>(row_st, csr_src, csr_norm,
                                                       dinv, zin, h, zo, N,
                                                       last ? 1 : 0);
        zin = zo;
    }
}